// Round 7
// baseline (142.734 us; speedup 1.0000x reference)
//
#include <hip/hip_runtime.h>
#include <math.h>

#define GRID_N 5
#define LOG2E 1.4426950408889634f
#define EXP2F __builtin_amdgcn_exp2f
#define BATCH 2048

// tanh + bin, with bin (1..5) packed into the low 3 mantissa bits of tanh(v).
// Perturbation <= 2^-21 relative — invisible downstream.
__device__ __forceinline__ unsigned pack_xn(float v) {
    float ex = EXP2F(2.0f * LOG2E * v);
    float t  = 1.0f - 2.0f / (ex + 1.0f);       // tanh(v), saturation-safe
    int k = (int)((t + 1.0f) * 2.0f) + 1;       // #{grid g <= t}, t in [-1,1]
    k = k > 5 ? 5 : k;
    return (__float_as_uint(t) & ~7u) | (unsigned)k;
}

// Per-(i,o) bin tables:  K = -s*log2e
//   A[k] = sum_{g_idx < k} w_g * 2^{-K*g},  B[k] = sum_{g_idx >= k} w_g * 2^{+K*g}
// T[i][k][o][2] = {A,B} (k=0..5);  Kt[i][o] = K
__device__ __forceinline__ void prep_one(const float* __restrict__ w,
                                         const float* __restrict__ s,
                                         float* __restrict__ T, float* __restrict__ Kt,
                                         int O, int I, int idx) {
    int o = idx / I, i = idx % I;               // w,s are [O][I(][G)]
    float K = -s[idx] * LOG2E;
    const float gv[5] = {-1.f, -0.5f, 0.f, 0.5f, 1.f};
    float A[6], B[6];
    A[0] = 0.f; B[5] = 0.f;
#pragma unroll
    for (int g = 0; g < 5; g++)
        A[g + 1] = A[g] + w[idx * GRID_N + g] * EXP2F(-K * gv[g]);
#pragma unroll
    for (int g = 4; g >= 0; g--)
        B[g] = B[g + 1] + w[idx * GRID_N + g] * EXP2F(K * gv[g]);
#pragma unroll
    for (int k = 0; k < 6; k++) {
        T[((i * 6 + k) * O + o) * 2 + 0] = A[k];
        T[((i * 6 + k) * O + o) * 2 + 1] = B[k];
    }
    Kt[i * O + o] = K;
}

// Tables for all 3 layers + pack x -> xp0
__global__ __launch_bounds__(256) void prep_all(
    const float* __restrict__ x,  unsigned* __restrict__ xp0,
    const float* __restrict__ w1, const float* __restrict__ s1, float* T1, float* K1,
    const float* __restrict__ w2, const float* __restrict__ s2, float* T2, float* K2,
    const float* __restrict__ w3, const float* __restrict__ s3, float* T3, float* K3) {
    int idx = blockIdx.x * 256 + threadIdx.x;
    if (idx < 262144) { xp0[idx] = pack_xn(x[idx]); return; }
    idx -= 262144;
    if (idx < 32768)       prep_one(w1, s1, T1, K1, 256, 128, idx);
    else if (idx < 65536)  prep_one(w2, s2, T2, K2, 128, 256, idx - 32768);
    else if (idx < 73728)  prep_one(w3, s3, T3, K3,  64, 128, idx - 65536);
}

// One KAN layer with LDS-staged table tiles.
//   out[b,o] = EPI( sum_i A[i,bin,o]*2^{K*xn} + B[i,bin,o]*2^{-K*xn} )
// Wave = 64 o's (lane=o) x BPT b-rows. Block = 4 waves sharing (oc, i-half):
// each tile (IT i's x 6 bins x 64 o's + K) staged to LDS once, read by all
// 4*BPT b-rows. xn packed (tanh + 3-bit bin) comes from the previous layer.
// IN = i's handled per kernel-half; HALVES: i-split (L2); XIN: 0=packed u32,
// 1=float partial pair p[idx]+p[PN+idx] -> relu -> pack inline (L3).
// EPI: 0 = relu+tanh+pack (u32), 1 = sigmoid (f32), 2 = raw partial (f32).
template<int IN, int OUT, int OCH, int BPT, int HALVES, int EPI, int XIN>
__global__ __launch_bounds__(256, 2) void kan_lds(
    const void* __restrict__ xin,
    const char* __restrict__ Tb,     // [IN*HALVES][6][OUT]{A,B} f32
    const char* __restrict__ Kb,     // [IN*HALVES][OUT] f32
    unsigned* __restrict__ op, float* __restrict__ of)
{
    constexpr int IT   = 16;                 // i's per LDS tile
    constexpr int CH   = IN / 64;
    constexpr int ABSZ = IT * 6 * 512;       // 49152 B
    constexpr int XSTR = IN * HALVES;        // xp row stride (XIN=0)
    __shared__ float4 ldsbuf[(ABSZ + IT * 256) / 16];   // 53248 B
    char* lds = (char*)ldsbuf;

    const int tid  = threadIdx.x;
    const int lane = tid & 63;
    const int w    = tid >> 6;
    const int h    = (HALVES > 1) ? (blockIdx.x % HALVES) : 0;
    const int q    = blockIdx.x / HALVES;
    const int oc   = q & (OCH - 1);
    const int bb   = q / OCH;
    const int o    = (oc << 6) | lane;
    const int bw   = bb * (4 * BPT) + w * BPT;

    if (HALVES > 1) {
        Tb += (size_t)h * IN * 6 * OUT * 8;
        Kb += (size_t)h * IN * OUT * 4;
        if (EPI == 2) of += (size_t)h * BATCH * OUT;
    }

    float acc[BPT];
#pragma unroll
    for (int j = 0; j < BPT; j++) acc[j] = 0.f;

    const int lane8 = lane << 3;
    const int lane4 = lane << 2;

#pragma unroll
    for (int c = 0; c < CH; c++) {
        // this wave's packed xn for i-chunk c (lane l holds i = c*64+l)
        unsigned xv[BPT];
#pragma unroll
        for (int j = 0; j < BPT; j++) {
            if (XIN == 0) {
                xv[j] = ((const unsigned*)xin + h * IN)[(bw + j) * XSTR + (c << 6) + lane];
            } else {
                const float* p = (const float*)xin;
                int e = (bw + j) * 128 + (c << 6) + lane;
                xv[j] = pack_xn(fmaxf(p[e] + p[262144 + e], 0.f));
            }
        }

#pragma unroll 1
        for (int tt = 0; tt < 64 / IT; tt++) {
            const int i0 = (c << 6) + tt * IT;
            __syncthreads();
            // stage AB: IT*6 rows x 512 B (this oc's 64-o slice)
#pragma unroll
            for (int it = 0; it < ABSZ / 4096; it++) {
                int e = (it * 256 + tid) << 4;
                int r = e >> 9, colb = e & 511;
                const char* src = Tb + (size_t)(i0 * 6 + r) * (OUT * 8) + (oc << 9) + colb;
                *(float4*)(lds + e) = *(const float4*)src;
            }
            // stage K: IT rows x 256 B (exactly 256 threads x 16 B)
            {
                int e = tid << 4;
                int r = e >> 8, colb = e & 255;
                const char* src = Kb + (size_t)(i0 + r) * (OUT * 4) + (oc << 8) + colb;
                *(float4*)(lds + ABSZ + e) = *(const float4*)src;
            }
            __syncthreads();
#pragma unroll
            for (int il = 0; il < IT; il++) {
                float K = *(const float*)(lds + ABSZ + il * 256 + lane4);
#pragma unroll
                for (int j = 0; j < BPT; j++) {
                    unsigned raw = (unsigned)__builtin_amdgcn_readlane((int)xv[j], tt * IT + il);
                    const float2 ab = *(const float2*)(lds + ((raw & 7u) << 9) + il * 3072 + lane8);
                    float xs = __uint_as_float(raw);
                    float t  = K * xs;
                    acc[j] += ab.x * EXP2F(t) + ab.y * EXP2F(-t);
                }
            }
        }
    }

#pragma unroll
    for (int j = 0; j < BPT; j++) {
        int b = bw + j;
        if (EPI == 0) {
            op[b * OUT + o] = pack_xn(fmaxf(acc[j], 0.f));
        } else if (EPI == 1) {
            of[b * OUT + o] = 1.0f / (1.0f + EXP2F(-LOG2E * acc[j]));
        } else {
            of[b * OUT + o] = acc[j];
        }
    }
}

extern "C" void kernel_launch(void* const* d_in, const int* in_sizes, int n_in,
                              void* d_out, int out_size, void* d_ws, size_t ws_size,
                              hipStream_t stream) {
    const float* x  = (const float*)d_in[0];
    const float* w1 = (const float*)d_in[1];
    const float* s1 = (const float*)d_in[2];
    const float* w2 = (const float*)d_in[3];
    const float* s2 = (const float*)d_in[4];
    const float* w3 = (const float*)d_in[5];
    const float* s3 = (const float*)d_in[6];
    float* out = (float*)d_out;

    float*    ws  = (float*)d_ws;
    unsigned* xp0 = (unsigned*)ws;      // 2048*128 = 262144
    unsigned* xp1 = xp0 + 262144;       // 2048*256 = 524288 (packed h1)
    float*    p2  = (float*)(xp1 + 524288); // 2*2048*128 = 524288 (L2 raw partials)
    float*    T1  = p2  + 524288;       // 128*6*256*2 = 393216
    float*    K1  = T1  + 393216;       // 32768
    float*    T2  = K1  + 32768;        // 256*6*128*2 = 393216
    float*    K2  = T2  + 393216;       // 32768
    float*    T3  = K2  + 32768;        // 128*6*64*2  = 98304
    float*    K3  = T3  + 98304;        // 8192

    prep_all<<<1312, 256, 0, stream>>>(x, xp0,
                                       w1, s1, T1, K1,
                                       w2, s2, T2, K2,
                                       w3, s3, T3, K3);

    // L1: IN=128,OUT=256,OCH=4,BPT=4 -> 128 bb * 4 oc = 512 blocks (2/CU)
    kan_lds<128, 256, 4, 4, 1, 0, 0><<<512, 256, 0, stream>>>(
        xp0, (const char*)T1, (const char*)K1, xp1, nullptr);
    // L2: 256 i's as 2 halves of 128; OUT=128,OCH=2,BPT=4 -> 128*2*2 = 512 blocks
    kan_lds<128, 128, 2, 4, 2, 2, 0><<<512, 256, 0, stream>>>(
        xp1, (const char*)T2, (const char*)K2, nullptr, p2);
    // L3: combines partial pair inline; IN=128,OUT=64,OCH=1,BPT=2 -> 256 blocks
    kan_lds<128, 64, 1, 2, 1, 1, 1><<<256, 256, 0, stream>>>(
        p2, (const char*)T3, (const char*)K3, nullptr, out);
}

// Round 8
// 101.057 us; speedup vs baseline: 1.4124x; 1.4124x over previous
//
#include <hip/hip_runtime.h>
#include <math.h>

#define GRID_N 5
#define LOG2E 1.4426950408889634f
#define EXP2F __builtin_amdgcn_exp2f
#define BATCH 2048

// Per-(i,o) bin tables:  K = -s*log2e
//   A[k] = sum_{g_idx < k} w_g * 2^{-K*g},  B[k] = sum_{g_idx >= k} w_g * 2^{+K*g}
// T[i][k][o][2] = {A,B} (k=0..5);  Kt[i][o] = K
__device__ __forceinline__ void prep_one(const float* __restrict__ w,
                                         const float* __restrict__ s,
                                         float* __restrict__ T, float* __restrict__ Kt,
                                         int O, int I, int idx) {
    int o = idx / I, i = idx % I;               // w,s are [O][I(][G)]
    float K = -s[idx] * LOG2E;
    const float gv[5] = {-1.f, -0.5f, 0.f, 0.5f, 1.f};
    float A[6], B[6];
    A[0] = 0.f; B[5] = 0.f;
#pragma unroll
    for (int g = 0; g < 5; g++)
        A[g + 1] = A[g] + w[idx * GRID_N + g] * EXP2F(-K * gv[g]);
#pragma unroll
    for (int g = 4; g >= 0; g--)
        B[g] = B[g + 1] + w[idx * GRID_N + g] * EXP2F(K * gv[g]);
#pragma unroll
    for (int k = 0; k < 6; k++) {
        T[((i * 6 + k) * O + o) * 2 + 0] = A[k];
        T[((i * 6 + k) * O + o) * 2 + 1] = B[k];
    }
    Kt[i * O + o] = K;
}

__global__ __launch_bounds__(256) void prep_all(
    const float* __restrict__ w1, const float* __restrict__ s1, float* T1, float* K1,
    const float* __restrict__ w2, const float* __restrict__ s2, float* T2, float* K2,
    const float* __restrict__ w3, const float* __restrict__ s3, float* T3, float* K3) {
    int idx = blockIdx.x * 256 + threadIdx.x;
    if (idx < 32768)       prep_one(w1, s1, T1, K1, 256, 128, idx);
    else if (idx < 65536)  prep_one(w2, s2, T2, K2, 128, 256, idx - 32768);
    else if (idx < 73728)  prep_one(w3, s3, T3, K3,  64, 128, idx - 65536);
}

// ---- software-pipelined KAN layer ----
// out[b,o] (+)= sum_{i in my half} A[i,bin,o]*2^{K*xn} + B[i,bin,o]*2^{-K*xn}
// Wave = 64 o's (lane=o) x BPT b-rows x LEN i's. Ping-pong batches of 8 i's:
// batch t+1's 24 loads issued (source order) before batch t's compute, all
// register indices static. amdgpu_waves_per_eu(4,4) => scheduler targets
// exactly 4 waves/EU, freeing it to use ~128 VGPRs for the pipeline.
// XMODE: 0 = xin raw floats [B][LEN*HALVES]; 1 = partial pair relu(p0+p1) (L3)
// EPI:   0 = relu f32; 1 = raw partial f32
#define LOADB(lb, AB, KV)                                                      \
    _Pragma("unroll")                                                          \
    for (int u = 0; u < 8; u++) {                                              \
        const int l  = (lb) * 8 + u;                                           \
        const int gi = hbase + c * 64 + l;                                     \
        KV[u] = Kt[gi * OUT + o];                                              \
        _Pragma("unroll")                                                      \
        for (int j = 0; j < BPT; j++) {                                        \
            unsigned os = (unsigned)__builtin_amdgcn_readlane((int)off[j][c], l); \
            AB[j][u] = *(const float2*)(Tb + (os + o8));                       \
        }                                                                      \
    }

#define COMPB(lb, AB, KV)                                                      \
    _Pragma("unroll")                                                          \
    for (int u = 0; u < 8; u++) {                                              \
        const int l = (lb) * 8 + u;                                            \
        _Pragma("unroll")                                                      \
        for (int j = 0; j < BPT; j++) {                                        \
            float xs = __int_as_float(__builtin_amdgcn_readlane(__float_as_int(xv[j][c]), l)); \
            float t  = KV[u] * xs;                                             \
            acc[j] += AB[j][u].x * EXP2F(t) + AB[j][u].y * EXP2F(-t);          \
        }                                                                      \
    }

template<int LEN, int OUT, int OCH, int BPT, int HALVES, int EPI, int XMODE>
__global__ __launch_bounds__(256) __attribute__((amdgpu_waves_per_eu(4, 4)))
void kan_pipe(const float* __restrict__ xin,
              const char*  __restrict__ Tb,    // [LEN*HALVES][6][OUT]{A,B} f32
              const float* __restrict__ Kt,    // [LEN*HALVES][OUT]
              float* __restrict__ outp)        // [HALVES][B][OUT]
{
    constexpr int CH   = LEN / 64;
    constexpr int NBG  = BATCH / BPT;
    constexpr int XSTR = LEN * HALVES;         // input row stride
    constexpr unsigned ROWB = OUT * 8;

    const int lane = threadIdx.x & 63;
    const int wid  = (blockIdx.x << 2) | (threadIdx.x >> 6);
    const int oc   = wid / (NBG * HALVES);
    const int rem  = wid % (NBG * HALVES);
    const int h    = rem / NBG;
    const int bg   = rem % NBG;
    const int o    = (oc << 6) | lane;
    const int b0   = bg * BPT;
    const int hbase = h * LEN;

    // stage: per-lane tanh + table byte-offset (lane l -> i = hbase + c*64 + l)
    float    xv[BPT][CH];
    unsigned off[BPT][CH];
#pragma unroll
    for (int j = 0; j < BPT; j++)
#pragma unroll
        for (int c = 0; c < CH; c++) {
            const int gi = hbase + (c << 6) + lane;
            float v;
            if (XMODE == 0) {
                v = xin[(b0 + j) * XSTR + gi];
            } else {
                int e = (b0 + j) * XSTR + gi;
                v = fmaxf(xin[e] + xin[BATCH * XSTR + e], 0.f);
            }
            float ex = EXP2F(2.0f * LOG2E * v);
            float t  = 1.0f - 2.0f / (ex + 1.0f);       // tanh, NaN-safe
            xv[j][c] = t;
            int k = (int)((t + 1.0f) * 2.0f) + 1;       // #{g <= t}
            k = k > 5 ? 5 : k;
            off[j][c] = (unsigned)(gi * 6 + k) * ROWB;
        }

    float acc[BPT];
#pragma unroll
    for (int j = 0; j < BPT; j++) acc[j] = 0.f;

    const unsigned o8 = (unsigned)o * 8u;

#pragma unroll
    for (int c = 0; c < CH; c++) {
        float2 abA[BPT][8], abB[BPT][8];
        float  KvA[8], KvB[8];
        LOADB(0, abA, KvA);
#pragma unroll
        for (int p = 0; p < 3; p++) {
            LOADB(2 * p + 1, abB, KvB);
            COMPB(2 * p,     abA, KvA);
            LOADB(2 * p + 2, abA, KvA);
            COMPB(2 * p + 1, abB, KvB);
        }
        LOADB(7, abB, KvB);
        COMPB(6, abA, KvA);
        COMPB(7, abB, KvB);
    }

#pragma unroll
    for (int j = 0; j < BPT; j++) {
        float z = acc[j];
        if (EPI == 0) z = fmaxf(z, 0.f);
        outp[(h * BATCH + (b0 + j)) * OUT + o] = z;
    }
}

// out[e] = sigmoid(p0[e] + p1[e])
__global__ __launch_bounds__(256) void sigmoid_combine(
    const float* __restrict__ p, float* __restrict__ out, int n) {
    int e = blockIdx.x * 256 + threadIdx.x;
    if (e >= n) return;
    float z = p[e] + p[n + e];
    out[e] = 1.0f / (1.0f + EXP2F(-LOG2E * z));
}

extern "C" void kernel_launch(void* const* d_in, const int* in_sizes, int n_in,
                              void* d_out, int out_size, void* d_ws, size_t ws_size,
                              hipStream_t stream) {
    const float* x  = (const float*)d_in[0];
    const float* w1 = (const float*)d_in[1];
    const float* s1 = (const float*)d_in[2];
    const float* w2 = (const float*)d_in[3];
    const float* s2 = (const float*)d_in[4];
    const float* w3 = (const float*)d_in[5];
    const float* s3 = (const float*)d_in[6];
    float* out = (float*)d_out;

    float* ws  = (float*)d_ws;
    float* h1  = ws;                    // 2048*256   = 524288 (aliased by p3 later)
    float* p2  = h1  + 524288;          // 2*2048*128 = 524288
    float* T1  = p2  + 524288;          // 128*6*256*2 = 393216
    float* K1  = T1  + 393216;          // 32768
    float* T2  = K1  + 32768;           // 256*6*128*2 = 393216
    float* K2  = T2  + 393216;          // 32768
    float* T3  = K2  + 32768;           // 128*6*64*2  = 98304
    float* K3  = T3  + 98304;           // 8192
    float* p3  = h1;                    // h1 dead after L2 (2*2048*64 = 262144)

    prep_all<<<288, 256, 0, stream>>>(w1, s1, T1, K1, w2, s2, T2, K2, w3, s3, T3, K3);

    // L1: LEN=128, OUT=256, OCH=4, BPT=2, HALVES=1 -> 4096 waves, 1024 blocks
    kan_pipe<128, 256, 4, 2, 1, 0, 0><<<1024, 256, 0, stream>>>(
        x, (const char*)T1, K1, h1);
    // L2: LEN=128 (2 halves of 256), OUT=128, OCH=2, BPT=2 -> 4096 waves, 1024 blocks
    kan_pipe<128, 128, 2, 2, 2, 1, 0><<<1024, 256, 0, stream>>>(
        h1, (const char*)T2, K2, p2);
    // L3: LEN=64 (2 halves of 128), OUT=64, OCH=1, BPT=2, XMODE=1 -> 2048 waves, 512 blocks
    kan_pipe<64, 64, 1, 2, 2, 1, 1><<<512, 256, 0, stream>>>(
        p2, (const char*)T3, K3, p3);
    // epilogue: sigmoid(p0+p1) -> out  (2048*64 = 131072 elems)
    sigmoid_combine<<<512, 256, 0, stream>>>(p3, out, 131072);
}